// Round 2
// baseline (1845.597 us; speedup 1.0000x reference)
//
#include <hip/hip_runtime.h>

#define NN 100000
#define NE 3200000
#define F 64
#define NR 8

// ---------------- zero the workspace (memset replacement, graph-safe) -------
__global__ __launch_bounds__(256) void zero_ws_kernel(float* __restrict__ p, long long n4) {
    // n4 = number of float4 elements
    long long i = (long long)blockIdx.x * 256 + threadIdx.x;
    long long stride = (long long)gridDim.x * 256;
    float4 z = make_float4(0.f, 0.f, 0.f, 0.f);
    for (; i < n4; i += stride)
        ((float4*)p)[i] = z;
}

// ---------------- scatter: one wave per edge (grid-stride), lane = feature --
__global__ __launch_bounds__(256) void scatter_kernel(
    const float* __restrict__ x,
    const int* __restrict__ edge_src,
    const int* __restrict__ edge_dst,
    const int* __restrict__ edge_type,
    float* __restrict__ agg, float* __restrict__ cnt)
{
    const int lane = threadIdx.x & 63;
    int wid = (blockIdx.x * 256 + threadIdx.x) >> 6;
    const int nw = (gridDim.x * 256) >> 6;
    for (int e = wid; e < NE; e += nw) {
        int src = edge_src[e];
        int dst = edge_dst[e];
        int r = edge_type[e];
        float v = x[(size_t)src * F + lane];
        atomicAdd(&agg[((size_t)dst * NR + r) * F + lane], v);
        if (lane == 0) atomicAdd(&cnt[dst * NR + r], 1.0f);
    }
}

// ---------------- transform: out = x@root + bias + sum_r (agg_r/cnt_r)@W_r --
// block = 256 threads = 4 waves; each wave handles 8 nodes (block: 32 nodes).
// lane = f_out. K processed in 9 segments of 64 (root, then W_0..W_7).
// W segment staged transposed in LDS: wt[fout][fin], row padded to 68 floats
// (272 B = 17 * 16 B, odd -> spreads b128 groups).
__global__ __launch_bounds__(256) void transform_kernel(
    const float* __restrict__ x,
    const float* __restrict__ agg,
    const float* __restrict__ cnt,
    const float* __restrict__ weight,   // [8][64][64]
    const float* __restrict__ root,     // [64][64]
    const float* __restrict__ bias,     // [64]
    float* __restrict__ out)
{
    __shared__ float wt[64][68];
    const int t = threadIdx.x;
    const int lane = t & 63;   // f_out
    const int strm = t >> 6;   // 0..3
    const int base = blockIdx.x * 32 + strm * 8; // NN % 32 == 0, always in range

    float acc[8];
    float b = bias[lane];
#pragma unroll
    for (int n = 0; n < 8; n++) acc[n] = b;

    for (int seg = 0; seg < 9; seg++) {
        const float* Wseg = (seg == 0) ? root : (weight + (size_t)(seg - 1) * (F * F));
        __syncthreads();
        for (int i = t; i < F * F; i += 256) {
            int fin = i >> 6, fo = i & 63;
            wt[fo][fin] = Wseg[i];   // transpose into LDS
        }
        __syncthreads();

        // per-node source row and scale
        const float* rowp[8];
        float scale[8];
#pragma unroll
        for (int n = 0; n < 8; n++) {
            if (seg == 0) {
                rowp[n] = x + (size_t)(base + n) * F;
                scale[n] = 1.0f;
            } else {
                rowp[n] = agg + ((size_t)(base + n) * NR + (seg - 1)) * F;
                float c = cnt[(base + n) * NR + (seg - 1)];
                scale[n] = 1.0f / fmaxf(c, 1.0f);
            }
        }

        float part[8];
#pragma unroll
        for (int n = 0; n < 8; n++) part[n] = 0.f;

        for (int f8 = 0; f8 < F; f8 += 8) {
            float4 wa = *(const float4*)&wt[lane][f8];
            float4 wb = *(const float4*)&wt[lane][f8 + 4];
#pragma unroll
            for (int n = 0; n < 8; n++) {
                float4 a0 = *(const float4*)(rowp[n] + f8);
                float4 a1 = *(const float4*)(rowp[n] + f8 + 4);
                part[n] += a0.x * wa.x + a0.y * wa.y + a0.z * wa.z + a0.w * wa.w
                         + a1.x * wb.x + a1.y * wb.y + a1.z * wb.z + a1.w * wb.w;
            }
        }

#pragma unroll
        for (int n = 0; n < 8; n++) acc[n] += part[n] * scale[n];
    }

#pragma unroll
    for (int n = 0; n < 8; n++)
        out[(size_t)(base + n) * F + lane] = acc[n];
}

extern "C" void kernel_launch(void* const* d_in, const int* in_sizes, int n_in,
                              void* d_out, int out_size, void* d_ws, size_t ws_size,
                              hipStream_t stream) {
    const float* x    = (const float*)d_in[0];
    const int*   ei   = (const int*)d_in[1];   // [2, NE]: row0 = src, row1 = dst
    const int*   et   = (const int*)d_in[2];
    const float* wgt  = (const float*)d_in[3];
    const float* root = (const float*)d_in[4];
    const float* bias = (const float*)d_in[5];
    float*       out  = (float*)d_out;

    float* cnt = (float*)d_ws;                                   // [NN*NR] fp32
    float* agg = (float*)((char*)d_ws + (size_t)NN * NR * 4);    // [NN*NR*F] fp32

    long long total_floats = (long long)NN * NR + (long long)NN * NR * F;  // 52M, %4==0
    zero_ws_kernel<<<4096, 256, 0, stream>>>((float*)d_ws, total_floats / 4);

    scatter_kernel<<<2048, 256, 0, stream>>>(x, ei, ei + NE, et, agg, cnt);
    transform_kernel<<<NN / 32, 256, 0, stream>>>(x, agg, cnt, wgt, root, bias, out);
}

// Round 3
// 1043.252 us; speedup vs baseline: 1.7691x; 1.7691x over previous
//
#include <hip/hip_runtime.h>

#define NN 100000
#define NE 3200000
#define F 64
#define NR 8
#define PAD 68   // LDS row stride (floats): 68%4==0 keeps b128 16B-aligned; lane groups differ by 4 banks -> worst 2-way (free)

// ---------------- zero the workspace (memset replacement, graph-safe) -------
__global__ __launch_bounds__(256) void zero_ws_kernel(float* __restrict__ p, long long n4) {
    long long i = (long long)blockIdx.x * 256 + threadIdx.x;
    long long stride = (long long)gridDim.x * 256;
    float4 z = make_float4(0.f, 0.f, 0.f, 0.f);
    for (; i < n4; i += stride)
        ((float4*)p)[i] = z;
}

// ---------------- scatter: one wave per edge (grid-stride), lane = feature --
__global__ __launch_bounds__(256) void scatter_kernel(
    const float* __restrict__ x,
    const int* __restrict__ edge_src,
    const int* __restrict__ edge_dst,
    const int* __restrict__ edge_type,
    float* __restrict__ agg, float* __restrict__ cnt)
{
    const int lane = threadIdx.x & 63;
    int wid = (blockIdx.x * 256 + threadIdx.x) >> 6;
    const int nw = (gridDim.x * 256) >> 6;
    for (int e = wid; e < NE; e += nw) {
        int src = edge_src[e];
        int dst = edge_dst[e];
        int r = edge_type[e];
        float v = x[(size_t)src * F + lane];
        atomicAdd(&agg[((size_t)dst * NR + r) * F + lane], v);
        if (lane == 0) atomicAdd(&cnt[dst * NR + r], 1.0f);
    }
}

// ---------------- transform: tiled GEMM ------------------------------------
// out[64 nodes x 64 fout] per block; K = 576 in 9 segments of 64
// (seg 0 = x @ root, seg r+1 = (agg_r * inv_cnt) @ W_r, scale folded at staging).
// As[k][node] (A transposed, coalesced stage), Bs[k][fout]. Thread = 4x4 tile.
__global__ __launch_bounds__(256) void transform_kernel(
    const float* __restrict__ x,
    const float* __restrict__ agg,
    const float* __restrict__ cnt,
    const float* __restrict__ weight,   // [8][64][64]
    const float* __restrict__ root,     // [64][64]
    const float* __restrict__ bias,     // [64]
    float* __restrict__ out)
{
    __shared__ float As[64][PAD];
    __shared__ float Bs[64][PAD];

    const int t  = threadIdx.x;
    const int tx = t & 15;    // fout group: fouts 4*tx..4*tx+3
    const int ty = t >> 4;    // node group: nodes 4*ty..4*ty+3
    const int node0 = blockIdx.x * 64;

    // A-staging mapping: each thread owns one node row quarter
    const int sn = t >> 2;    // node within tile 0..63
    const int sq = t & 3;     // quarter 0..3

    float acc[4][4];
#pragma unroll
    for (int i = 0; i < 4; i++)
#pragma unroll
        for (int j = 0; j < 4; j++) acc[i][j] = 0.f;

    const int nclamp = min(node0 + sn, NN - 1);

    for (int seg = 0; seg < 9; seg++) {
        const float* __restrict__ Wseg = (seg == 0) ? root : (weight + (size_t)(seg - 1) * (F * F));

        __syncthreads();
        // stage B: 4096 floats, 4x float4 per thread, coalesced
#pragma unroll
        for (int j = 0; j < 4; j++) {
            int g = j * 1024 + t * 4;
            float4 v = *(const float4*)(Wseg + g);
            *(float4*)&Bs[g >> 6][g & 63] = v;
        }
        // stage A transposed + scaled
        const float* rowp;
        float scl;
        if (seg == 0) {
            rowp = x + (size_t)nclamp * F;
            scl = 1.0f;
        } else {
            int r = seg - 1;
            rowp = agg + ((size_t)nclamp * NR + r) * F;
            float cn = cnt[nclamp * NR + r];
            scl = 1.0f / fmaxf(cn, 1.0f);
        }
#pragma unroll
        for (int j = 0; j < 4; j++) {
            int kc = (sq + j * 4) * 4;   // k chunk base
            float4 v = *(const float4*)(rowp + kc);
            As[kc + 0][sn] = v.x * scl;
            As[kc + 1][sn] = v.y * scl;
            As[kc + 2][sn] = v.z * scl;
            As[kc + 3][sn] = v.w * scl;
        }
        __syncthreads();

#pragma unroll 8
        for (int k = 0; k < 64; k++) {
            float4 a = *(const float4*)&As[k][ty << 2];
            float4 b = *(const float4*)&Bs[k][tx << 2];
            acc[0][0] = fmaf(a.x, b.x, acc[0][0]);
            acc[0][1] = fmaf(a.x, b.y, acc[0][1]);
            acc[0][2] = fmaf(a.x, b.z, acc[0][2]);
            acc[0][3] = fmaf(a.x, b.w, acc[0][3]);
            acc[1][0] = fmaf(a.y, b.x, acc[1][0]);
            acc[1][1] = fmaf(a.y, b.y, acc[1][1]);
            acc[1][2] = fmaf(a.y, b.z, acc[1][2]);
            acc[1][3] = fmaf(a.y, b.w, acc[1][3]);
            acc[2][0] = fmaf(a.z, b.x, acc[2][0]);
            acc[2][1] = fmaf(a.z, b.y, acc[2][1]);
            acc[2][2] = fmaf(a.z, b.z, acc[2][2]);
            acc[2][3] = fmaf(a.z, b.w, acc[2][3]);
            acc[3][0] = fmaf(a.w, b.x, acc[3][0]);
            acc[3][1] = fmaf(a.w, b.y, acc[3][1]);
            acc[3][2] = fmaf(a.w, b.z, acc[3][2]);
            acc[3][3] = fmaf(a.w, b.w, acc[3][3]);
        }
    }

    // epilogue: + bias, coalesced float4 stores
    float4 bv = *(const float4*)(bias + (tx << 2));
#pragma unroll
    for (int i = 0; i < 4; i++) {
        int node = node0 + (ty << 2) + i;
        if (node < NN) {
            float4 o = make_float4(acc[i][0] + bv.x, acc[i][1] + bv.y,
                                   acc[i][2] + bv.z, acc[i][3] + bv.w);
            *(float4*)(out + (size_t)node * F + (tx << 2)) = o;
        }
    }
}

extern "C" void kernel_launch(void* const* d_in, const int* in_sizes, int n_in,
                              void* d_out, int out_size, void* d_ws, size_t ws_size,
                              hipStream_t stream) {
    const float* x    = (const float*)d_in[0];
    const int*   ei   = (const int*)d_in[1];   // [2, NE]: row0 = src, row1 = dst
    const int*   et   = (const int*)d_in[2];
    const float* wgt  = (const float*)d_in[3];
    const float* root = (const float*)d_in[4];
    const float* bias = (const float*)d_in[5];
    float*       out  = (float*)d_out;

    float* cnt = (float*)d_ws;                                   // [NN*NR]
    float* agg = (float*)((char*)d_ws + (size_t)NN * NR * 4);    // [NN*NR*F]

    long long total_floats = (long long)NN * NR + (long long)NN * NR * F;  // %4==0
    zero_ws_kernel<<<4096, 256, 0, stream>>>((float*)d_ws, total_floats / 4);

    scatter_kernel<<<2048, 256, 0, stream>>>(x, ei, ei + NE, et, agg, cnt);

    int tblocks = (NN + 63) / 64;  // 1563, last block partially masked
    transform_kernel<<<tblocks, 256, 0, stream>>>(x, agg, cnt, wgt, root, bias, out);
}

// Round 4
// 662.279 us; speedup vs baseline: 2.7867x; 1.5752x over previous
//
#include <hip/hip_runtime.h>

#define NN 100000
#define NE 3200000
#define F 64
#define NR 8
#define NK (NR * NN)          // 800000 sort keys (rel-major: key = r*NN + dst)
#define PAD 68                // LDS row stride in floats
#define SCAN_ITEMS 2048
#define SCAN_BLOCKS ((NK + SCAN_ITEMS - 1) / SCAN_ITEMS)   // 391

// ---------------- zero the histogram (graph-safe memset) --------------------
__global__ __launch_bounds__(256) void zero_hist_kernel(int4* __restrict__ p, int n4) {
    int i = blockIdx.x * 256 + threadIdx.x;
    int stride = gridDim.x * 256;
    int4 z = make_int4(0, 0, 0, 0);
    for (; i < n4; i += stride) p[i] = z;
}

// ---------------- pass 1: histogram of (rel, dst) ---------------------------
__global__ __launch_bounds__(256) void hist_kernel(
    const int* __restrict__ edge_dst, const int* __restrict__ edge_type,
    int* __restrict__ hist)
{
    int e = blockIdx.x * 256 + threadIdx.x;   // grid sized exactly: NE/256
    int key = edge_type[e] * NN + edge_dst[e];
    atomicAdd(&hist[key], 1);
}

// ---------------- pass 2a: per-block exclusive scan -------------------------
__global__ __launch_bounds__(256) void scan1_kernel(
    const int* __restrict__ hist, int* __restrict__ offsets, int* __restrict__ bsum)
{
    __shared__ int sh[256];
    const int t = threadIdx.x;
    const int base = blockIdx.x * SCAN_ITEMS + t * 8;
    int v[8], s = 0;
#pragma unroll
    for (int i = 0; i < 8; i++) {
        int idx = base + i;
        v[i] = (idx < NK) ? hist[idx] : 0;
        s += v[i];
    }
    sh[t] = s;
    __syncthreads();
    for (int off = 1; off < 256; off <<= 1) {
        int add = (t >= off) ? sh[t - off] : 0;
        __syncthreads();
        sh[t] += add;
        __syncthreads();
    }
    int run = sh[t] - s;   // exclusive prefix of this thread's first item
    if (t == 255) bsum[blockIdx.x] = sh[255];
#pragma unroll
    for (int i = 0; i < 8; i++) {
        int idx = base + i;
        if (idx < NK) offsets[idx] = run;
        run += v[i];
    }
}

// ---------------- pass 2b: scan the 391 block sums (single block) -----------
__global__ __launch_bounds__(512) void scan2_kernel(int* __restrict__ bsum) {
    __shared__ int sh[512];
    const int t = threadIdx.x;
    int v = (t < SCAN_BLOCKS) ? bsum[t] : 0;
    sh[t] = v;
    __syncthreads();
    for (int off = 1; off < 512; off <<= 1) {
        int add = (t >= off) ? sh[t - off] : 0;
        __syncthreads();
        sh[t] += add;
        __syncthreads();
    }
    if (t < SCAN_BLOCKS) bsum[t] = sh[t] - v;   // exclusive
}

// ---------------- pass 2c: add block offsets; also init cursor --------------
__global__ __launch_bounds__(256) void scan3_kernel(
    int* __restrict__ offsets, const int* __restrict__ bsum, int* __restrict__ cursor)
{
    const int off = bsum[blockIdx.x];
    const int base = blockIdx.x * SCAN_ITEMS + threadIdx.x;
#pragma unroll
    for (int i = 0; i < 8; i++) {
        int idx = base + i * 256;
        if (idx < NK) {
            int vv = offsets[idx] + off;
            offsets[idx] = vv;
            cursor[idx] = vv;
        }
    }
}

// ---------------- pass 3: place src ids into CSR order ----------------------
__global__ __launch_bounds__(256) void fill_kernel(
    const int* __restrict__ edge_src, const int* __restrict__ edge_dst,
    const int* __restrict__ edge_type,
    int* __restrict__ cursor, int* __restrict__ sorted_src)
{
    int e = blockIdx.x * 256 + threadIdx.x;
    int key = edge_type[e] * NN + edge_dst[e];
    int pos = atomicAdd(&cursor[key], 1);
    sorted_src[pos] = edge_src[e];
}

// ---------------- fused gather-mean + GEMM ----------------------------------
// out[64 nodes x 64 fout] per block; K = 576 in 9 segments of 64.
// seg 0: As <- x rows. seg r+1: As <- mean of gathered x[src] rows (registers,
// no agg materialization). Bs <- [root; W_r]. Thread computes a 4x4 tile.
// A-stage partition: 4 threads per node, thread sq owns k-chunks
// {4sq, 4sq+16, 4sq+32, 4sq+48} (+0..3): LDS write aliasing worst 2-way (free).
__global__ __launch_bounds__(256) void fused_kernel(
    const float* __restrict__ x,
    const int* __restrict__ sorted_src,
    const int* __restrict__ offsets,
    const int* __restrict__ hist,
    const float* __restrict__ weight,   // [8][64][64]
    const float* __restrict__ root,     // [64][64]
    const float* __restrict__ bias,     // [64]
    float* __restrict__ out)
{
    __shared__ float As[64][PAD];
    __shared__ float Bs[64][PAD];

    const int t  = threadIdx.x;
    const int tx = t & 15;    // fout group
    const int ty = t >> 4;    // node group
    const int node0 = blockIdx.x * 64;
    const int sn = t >> 2;    // staging node 0..63
    const int sq = t & 3;     // staging quarter 0..3
    const int nclamp = min(node0 + sn, NN - 1);

    float acc[4][4];
#pragma unroll
    for (int i = 0; i < 4; i++)
#pragma unroll
        for (int j = 0; j < 4; j++) acc[i][j] = 0.f;

    for (int seg = 0; seg < 9; seg++) {
        const float* __restrict__ Wseg = (seg == 0) ? root : (weight + (size_t)(seg - 1) * (F * F));

        __syncthreads();
        // stage B: 4096 floats, 4x float4 per thread, coalesced
#pragma unroll
        for (int j = 0; j < 4; j++) {
            int g = j * 1024 + t * 4;
            float4 v = *(const float4*)(Wseg + g);
            *(float4*)&Bs[g >> 6][g & 63] = v;
        }

        // stage A
        if (seg == 0) {
            const float* xr = x + (size_t)nclamp * F + (sq << 2);
            float4 v0 = *(const float4*)(xr);
            float4 v1 = *(const float4*)(xr + 16);
            float4 v2 = *(const float4*)(xr + 32);
            float4 v3 = *(const float4*)(xr + 48);
            int k0 = sq << 2;
            As[k0 +  0][sn] = v0.x; As[k0 +  1][sn] = v0.y; As[k0 +  2][sn] = v0.z; As[k0 +  3][sn] = v0.w;
            As[k0 + 16][sn] = v1.x; As[k0 + 17][sn] = v1.y; As[k0 + 18][sn] = v1.z; As[k0 + 19][sn] = v1.w;
            As[k0 + 32][sn] = v2.x; As[k0 + 33][sn] = v2.y; As[k0 + 34][sn] = v2.z; As[k0 + 35][sn] = v2.w;
            As[k0 + 48][sn] = v3.x; As[k0 + 49][sn] = v3.y; As[k0 + 50][sn] = v3.z; As[k0 + 51][sn] = v3.w;
        } else {
            const int key = (seg - 1) * NN + nclamp;
            const int beg = offsets[key];
            const int cnt = hist[key];
            float4 a0 = make_float4(0.f, 0.f, 0.f, 0.f);
            float4 a1 = a0, a2 = a0, a3 = a0;
            const int* sp = sorted_src + beg;
            for (int i = 0; i < cnt; i++) {
                const float* xr = x + (size_t)sp[i] * F + (sq << 2);
                float4 v0 = *(const float4*)(xr);
                float4 v1 = *(const float4*)(xr + 16);
                float4 v2 = *(const float4*)(xr + 32);
                float4 v3 = *(const float4*)(xr + 48);
                a0.x += v0.x; a0.y += v0.y; a0.z += v0.z; a0.w += v0.w;
                a1.x += v1.x; a1.y += v1.y; a1.z += v1.z; a1.w += v1.w;
                a2.x += v2.x; a2.y += v2.y; a2.z += v2.z; a2.w += v2.w;
                a3.x += v3.x; a3.y += v3.y; a3.z += v3.z; a3.w += v3.w;
            }
            float scl = 1.0f / (float)max(cnt, 1);
            int k0 = sq << 2;
            As[k0 +  0][sn] = a0.x * scl; As[k0 +  1][sn] = a0.y * scl; As[k0 +  2][sn] = a0.z * scl; As[k0 +  3][sn] = a0.w * scl;
            As[k0 + 16][sn] = a1.x * scl; As[k0 + 17][sn] = a1.y * scl; As[k0 + 18][sn] = a1.z * scl; As[k0 + 19][sn] = a1.w * scl;
            As[k0 + 32][sn] = a2.x * scl; As[k0 + 33][sn] = a2.y * scl; As[k0 + 34][sn] = a2.z * scl; As[k0 + 35][sn] = a2.w * scl;
            As[k0 + 48][sn] = a3.x * scl; As[k0 + 49][sn] = a3.y * scl; As[k0 + 50][sn] = a3.z * scl; As[k0 + 51][sn] = a3.w * scl;
        }
        __syncthreads();

#pragma unroll 8
        for (int k = 0; k < 64; k++) {
            float4 a = *(const float4*)&As[k][ty << 2];
            float4 b = *(const float4*)&Bs[k][tx << 2];
            acc[0][0] = fmaf(a.x, b.x, acc[0][0]);
            acc[0][1] = fmaf(a.x, b.y, acc[0][1]);
            acc[0][2] = fmaf(a.x, b.z, acc[0][2]);
            acc[0][3] = fmaf(a.x, b.w, acc[0][3]);
            acc[1][0] = fmaf(a.y, b.x, acc[1][0]);
            acc[1][1] = fmaf(a.y, b.y, acc[1][1]);
            acc[1][2] = fmaf(a.y, b.z, acc[1][2]);
            acc[1][3] = fmaf(a.y, b.w, acc[1][3]);
            acc[2][0] = fmaf(a.z, b.x, acc[2][0]);
            acc[2][1] = fmaf(a.z, b.y, acc[2][1]);
            acc[2][2] = fmaf(a.z, b.z, acc[2][2]);
            acc[2][3] = fmaf(a.z, b.w, acc[2][3]);
            acc[3][0] = fmaf(a.w, b.x, acc[3][0]);
            acc[3][1] = fmaf(a.w, b.y, acc[3][1]);
            acc[3][2] = fmaf(a.w, b.z, acc[3][2]);
            acc[3][3] = fmaf(a.w, b.w, acc[3][3]);
        }
    }

    // epilogue: + bias, coalesced float4 stores
    float4 bv = *(const float4*)(bias + (tx << 2));
#pragma unroll
    for (int i = 0; i < 4; i++) {
        int node = node0 + (ty << 2) + i;
        if (node < NN) {
            float4 o = make_float4(acc[i][0] + bv.x, acc[i][1] + bv.y,
                                   acc[i][2] + bv.z, acc[i][3] + bv.w);
            *(float4*)(out + (size_t)node * F + (tx << 2)) = o;
        }
    }
}

extern "C" void kernel_launch(void* const* d_in, const int* in_sizes, int n_in,
                              void* d_out, int out_size, void* d_ws, size_t ws_size,
                              hipStream_t stream) {
    const float* x    = (const float*)d_in[0];
    const int*   ei   = (const int*)d_in[1];   // [2, NE]: row0 = src, row1 = dst
    const int*   et   = (const int*)d_in[2];
    const float* wgt  = (const float*)d_in[3];
    const float* root = (const float*)d_in[4];
    const float* bias = (const float*)d_in[5];
    float*       out  = (float*)d_out;

    // workspace layout (ints)
    int* hist       = (int*)d_ws;                       // [NK]
    int* offsets    = hist + NK;                        // [NK]
    int* cursor     = offsets + NK;                     // [NK]
    int* bsum       = cursor + NK;                      // [512]
    int* sorted_src = bsum + 512;                       // [NE]

    zero_hist_kernel<<<256, 256, 0, stream>>>((int4*)hist, NK / 4);
    hist_kernel<<<NE / 256, 256, 0, stream>>>(ei + NE, et, hist);
    scan1_kernel<<<SCAN_BLOCKS, 256, 0, stream>>>(hist, offsets, bsum);
    scan2_kernel<<<1, 512, 0, stream>>>(bsum);
    scan3_kernel<<<SCAN_BLOCKS, 256, 0, stream>>>(offsets, bsum, cursor);
    fill_kernel<<<NE / 256, 256, 0, stream>>>(ei, ei + NE, et, cursor, sorted_src);

    int tblocks = (NN + 63) / 64;  // 1563
    fused_kernel<<<tblocks, 256, 0, stream>>>(x, sorted_src, offsets, hist,
                                              wgt, root, bias, out);
}

// Round 5
// 382.100 us; speedup vs baseline: 4.8301x; 1.7333x over previous
//
#include <hip/hip_runtime.h>

#define NN 100000
#define NE 3200000
#define F 64
#define NR 8
#define PAD 68                 // LDS row stride (floats) for As/Bs
#define NCB 98                 // coarse buckets = ceil(NN/1024), bucket = dst>>10
#define CAPC 36864             // capacity per coarse bucket (mean 32768, +6 sigma safe)
#define CHUNK 4000             // edges per binA block (800 blocks x 4000 = NE)
#define SLCAP 2816             // per-tile sorted list capacity (mean 2048, +17 sigma)
#define NTILE 1563             // ceil(NN/64)

// ---------------- init: per-coarse-bucket staging cursors -------------------
__global__ __launch_bounds__(128) void init_kernel(int* __restrict__ cursors) {
    int t = threadIdx.x;
    if (t < NCB) cursors[t] = t * CAPC;
}

// ---------------- pass A: coarse-bin edges (LDS multi-split, burst writes) --
__global__ __launch_bounds__(256) void binA_kernel(
    const int* __restrict__ edge_src, const int* __restrict__ edge_dst,
    const int* __restrict__ edge_type,
    int* __restrict__ cursors, uint2* __restrict__ stag8)
{
    __shared__ int hist[128];
    __shared__ int start[128];
    __shared__ int cur[NCB];
    __shared__ int gbase[NCB];
    __shared__ uint2 recs[CHUNK];   // 32 KB

    const int t = threadIdx.x;
    const int e0 = blockIdx.x * CHUNK;

    if (t < 128) hist[t] = 0;
    __syncthreads();

    uint2 rec[16];
#pragma unroll
    for (int j = 0; j < 16; j++) {
        int i = t + j * 256;
        if (i < CHUNK) {
            int e = e0 + i;
            unsigned s = (unsigned)edge_src[e];
            unsigned d = (unsigned)edge_dst[e];
            unsigned r = (unsigned)edge_type[e];
            rec[j] = make_uint2(s, d | (r << 17));
            atomicAdd(&hist[d >> 10], 1);
        }
    }
    __syncthreads();

    // exclusive scan of 128 counters (Hillis-Steele on threads 0..127)
    if (t < 128) start[t] = hist[t];
    __syncthreads();
    for (int off = 1; off < 128; off <<= 1) {
        int v = 0;
        if (t < 128 && t >= off) v = start[t - off];
        __syncthreads();
        if (t < 128) start[t] += v;
        __syncthreads();
    }
    if (t < 128) start[t] -= hist[t];   // inclusive -> exclusive
    __syncthreads();
    if (t < NCB) {
        cur[t] = start[t];
        gbase[t] = atomicAdd(&cursors[t], hist[t]);   // reserve global run
    }
    __syncthreads();

    // scatter into LDS grouped by bucket (order within bucket irrelevant: mean)
#pragma unroll
    for (int j = 0; j < 16; j++) {
        int i = t + j * 256;
        if (i < CHUNK) {
            int b = (int)((rec[j].y & 0x1FFFFu) >> 10);
            int slot = atomicAdd(&cur[b], 1);
            recs[slot] = rec[j];
        }
    }
    __syncthreads();

    // burst write-out: lane-consecutive slots -> consecutive global addrs
#pragma unroll
    for (int j = 0; j < 16; j++) {
        int i = t + j * 256;
        if (i < CHUNK) {
            uint2 rr = recs[i];
            int b = (int)((rr.y & 0x1FFFFu) >> 10);
            stag8[gbase[b] + (i - start[b])] = rr;
        }
    }
}

// ---------------- pass B: fine-bin each coarse bucket into 16 node tiles ----
// One block per coarse bucket: scatter region ~130 KB -> stays in one XCD L2.
__global__ __launch_bounds__(256) void binB_kernel(
    const uint2* __restrict__ stag8, const int* __restrict__ cursors,
    unsigned* __restrict__ packed4,
    int* __restrict__ tile_start, int* __restrict__ tile_cnt)
{
    __shared__ int h[16], st[16], cu[16];
    const int b = blockIdx.x;
    const int t = threadIdx.x;
    const int base = b * CAPC;
    const int n = cursors[b] - base;

    if (t < 16) h[t] = 0;
    __syncthreads();
    for (int i = t; i < n; i += 256) {
        unsigned y = stag8[base + i].y;
        atomicAdd(&h[(y >> 6) & 15], 1);
    }
    __syncthreads();
    if (t == 0) {
        int acc = 0;
        for (int f = 0; f < 16; f++) { st[f] = acc; cu[f] = acc; acc += h[f]; }
    }
    __syncthreads();
    for (int i = t; i < n; i += 256) {
        uint2 rr = stag8[base + i];
        unsigned f = (rr.y >> 6) & 15u;
        int p = atomicAdd(&cu[f], 1);
        unsigned d = rr.y & 0x1FFFFu;
        unsigned r = rr.y >> 17;
        // packed: src[0:17) | dstLow6[17:23) | rel[23:26)
        packed4[base + p] = rr.x | ((d & 63u) << 17) | (r << 23);
    }
    __syncthreads();
    if (t < 16) {
        tile_start[b * 16 + t] = base + st[t];
        tile_cnt[b * 16 + t] = h[t];
    }
}

// ---------------- fused: LDS counting-sort + gather-mean + GEMM -------------
// out[64 nodes x 64 fout] per block; K = 576 in 9 segments of 64.
__global__ __launch_bounds__(256) void fused_kernel(
    const float* __restrict__ x,
    const unsigned* __restrict__ packed4,
    const int* __restrict__ tile_start, const int* __restrict__ tile_cnt,
    const float* __restrict__ weight,   // [8][64][64]
    const float* __restrict__ root,     // [64][64]
    const float* __restrict__ bias,     // [64]
    float* __restrict__ out)
{
    __shared__ float As[64][PAD];
    __shared__ float Bs[64][PAD];
    __shared__ int kstart[512];   // counts -> run starts
    __shared__ int kcur[512];     // scan temp -> cursor -> run ends
    __shared__ int slist[SLCAP];  // sorted src ids

    const int t  = threadIdx.x;
    const int tile = blockIdx.x;
    const int s0 = tile_start[tile];
    const int c  = tile_cnt[tile];

    // ---- LDS counting sort by key9 = rel*64 + dstLow ----
    kstart[t] = 0; kstart[t + 256] = 0;
    __syncthreads();
    for (int i = t; i < c; i += 256) {
        unsigned p = packed4[s0 + i];
        atomicAdd(&kstart[p >> 17], 1);
    }
    __syncthreads();
    int a0 = kstart[2 * t], a1 = kstart[2 * t + 1];
    int psum = a0 + a1;
    kcur[t] = psum;
    __syncthreads();
    for (int off = 1; off < 256; off <<= 1) {
        int v = (t >= off) ? kcur[t - off] : 0;
        __syncthreads();
        kcur[t] += v;
        __syncthreads();
    }
    int ebase = kcur[t] - psum;   // exclusive over thread pairs
    __syncthreads();
    kstart[2 * t]     = ebase;
    kstart[2 * t + 1] = ebase + a0;
    kcur[2 * t]       = ebase;
    kcur[2 * t + 1]   = ebase + a0;
    __syncthreads();
    for (int i = t; i < c; i += 256) {
        unsigned p = packed4[s0 + i];
        int slot = atomicAdd(&kcur[p >> 17], 1);
        slist[slot] = (int)(p & 0x1FFFFu);
    }
    // now kcur[k] == end of run k
    __syncthreads();

    // ---- GEMM ----
    const int tx = t & 15;    // fout group
    const int ty = t >> 4;    // node group
    const int node0 = tile * 64;
    const int sn = t >> 2;    // staging node 0..63
    const int sq = t & 3;     // staging quarter 0..3
    const int nclamp = min(node0 + sn, NN - 1);

    float acc[4][4];
#pragma unroll
    for (int i = 0; i < 4; i++)
#pragma unroll
        for (int j = 0; j < 4; j++) acc[i][j] = 0.f;

    for (int seg = 0; seg < 9; seg++) {
        const float* __restrict__ Wseg = (seg == 0) ? root : (weight + (size_t)(seg - 1) * (F * F));

        __syncthreads();
        // stage B: 4096 floats, 4x float4 per thread, coalesced
#pragma unroll
        for (int j = 0; j < 4; j++) {
            int g = j * 1024 + t * 4;
            float4 v = *(const float4*)(Wseg + g);
            *(float4*)&Bs[g >> 6][g & 63] = v;
        }

        // stage A
        if (seg == 0) {
            const float* xr = x + (size_t)nclamp * F + (sq << 2);
            float4 v0 = *(const float4*)(xr);
            float4 v1 = *(const float4*)(xr + 16);
            float4 v2 = *(const float4*)(xr + 32);
            float4 v3 = *(const float4*)(xr + 48);
            int k0 = sq << 2;
            As[k0 +  0][sn] = v0.x; As[k0 +  1][sn] = v0.y; As[k0 +  2][sn] = v0.z; As[k0 +  3][sn] = v0.w;
            As[k0 + 16][sn] = v1.x; As[k0 + 17][sn] = v1.y; As[k0 + 18][sn] = v1.z; As[k0 + 19][sn] = v1.w;
            As[k0 + 32][sn] = v2.x; As[k0 + 33][sn] = v2.y; As[k0 + 34][sn] = v2.z; As[k0 + 35][sn] = v2.w;
            As[k0 + 48][sn] = v3.x; As[k0 + 49][sn] = v3.y; As[k0 + 50][sn] = v3.z; As[k0 + 51][sn] = v3.w;
        } else {
            const int key = ((seg - 1) << 6) | sn;
            const int beg = kstart[key];
            const int end = kcur[key];
            float4 a0v = make_float4(0.f, 0.f, 0.f, 0.f);
            float4 a1v = a0v, a2v = a0v, a3v = a0v;
            for (int i = beg; i < end; i++) {
                const float* xr = x + (size_t)slist[i] * F + (sq << 2);
                float4 v0 = *(const float4*)(xr);
                float4 v1 = *(const float4*)(xr + 16);
                float4 v2 = *(const float4*)(xr + 32);
                float4 v3 = *(const float4*)(xr + 48);
                a0v.x += v0.x; a0v.y += v0.y; a0v.z += v0.z; a0v.w += v0.w;
                a1v.x += v1.x; a1v.y += v1.y; a1v.z += v1.z; a1v.w += v1.w;
                a2v.x += v2.x; a2v.y += v2.y; a2v.z += v2.z; a2v.w += v2.w;
                a3v.x += v3.x; a3v.y += v3.y; a3v.z += v3.z; a3v.w += v3.w;
            }
            float scl = 1.0f / (float)max(end - beg, 1);
            int k0 = sq << 2;
            As[k0 +  0][sn] = a0v.x * scl; As[k0 +  1][sn] = a0v.y * scl; As[k0 +  2][sn] = a0v.z * scl; As[k0 +  3][sn] = a0v.w * scl;
            As[k0 + 16][sn] = a1v.x * scl; As[k0 + 17][sn] = a1v.y * scl; As[k0 + 18][sn] = a1v.z * scl; As[k0 + 19][sn] = a1v.w * scl;
            As[k0 + 32][sn] = a2v.x * scl; As[k0 + 33][sn] = a2v.y * scl; As[k0 + 34][sn] = a2v.z * scl; As[k0 + 35][sn] = a2v.w * scl;
            As[k0 + 48][sn] = a3v.x * scl; As[k0 + 49][sn] = a3v.y * scl; As[k0 + 50][sn] = a3v.z * scl; As[k0 + 51][sn] = a3v.w * scl;
        }
        __syncthreads();

#pragma unroll 8
        for (int k = 0; k < 64; k++) {
            float4 a = *(const float4*)&As[k][ty << 2];
            float4 b = *(const float4*)&Bs[k][tx << 2];
            acc[0][0] = fmaf(a.x, b.x, acc[0][0]);
            acc[0][1] = fmaf(a.x, b.y, acc[0][1]);
            acc[0][2] = fmaf(a.x, b.z, acc[0][2]);
            acc[0][3] = fmaf(a.x, b.w, acc[0][3]);
            acc[1][0] = fmaf(a.y, b.x, acc[1][0]);
            acc[1][1] = fmaf(a.y, b.y, acc[1][1]);
            acc[1][2] = fmaf(a.y, b.z, acc[1][2]);
            acc[1][3] = fmaf(a.y, b.w, acc[1][3]);
            acc[2][0] = fmaf(a.z, b.x, acc[2][0]);
            acc[2][1] = fmaf(a.z, b.y, acc[2][1]);
            acc[2][2] = fmaf(a.z, b.z, acc[2][2]);
            acc[2][3] = fmaf(a.z, b.w, acc[2][3]);
            acc[3][0] = fmaf(a.w, b.x, acc[3][0]);
            acc[3][1] = fmaf(a.w, b.y, acc[3][1]);
            acc[3][2] = fmaf(a.w, b.z, acc[3][2]);
            acc[3][3] = fmaf(a.w, b.w, acc[3][3]);
        }
    }

    // epilogue: + bias, coalesced float4 stores
    float4 bv = *(const float4*)(bias + (tx << 2));
#pragma unroll
    for (int i = 0; i < 4; i++) {
        int node = node0 + (ty << 2) + i;
        if (node < NN) {
            float4 o = make_float4(acc[i][0] + bv.x, acc[i][1] + bv.y,
                                   acc[i][2] + bv.z, acc[i][3] + bv.w);
            *(float4*)(out + (size_t)node * F + (tx << 2)) = o;
        }
    }
}

extern "C" void kernel_launch(void* const* d_in, const int* in_sizes, int n_in,
                              void* d_out, int out_size, void* d_ws, size_t ws_size,
                              hipStream_t stream) {
    const float* x    = (const float*)d_in[0];
    const int*   ei   = (const int*)d_in[1];   // [2, NE]: row0 = src, row1 = dst
    const int*   et   = (const int*)d_in[2];
    const float* wgt  = (const float*)d_in[3];
    const float* root = (const float*)d_in[4];
    const float* bias = (const float*)d_in[5];
    float*       out  = (float*)d_out;

    // workspace layout
    int*      cursors    = (int*)d_ws;                 // [128]
    int*      tile_start = cursors + 128;              // [1568]
    int*      tile_cnt   = tile_start + 1568;          // [1568]
    uint2*    stag8      = (uint2*)(tile_cnt + 1568);  // [NCB*CAPC] 8B recs (28.9 MB)
    unsigned* packed4    = (unsigned*)(stag8 + (size_t)NCB * CAPC); // [NCB*CAPC] 4B (14.5 MB)

    init_kernel<<<1, 128, 0, stream>>>(cursors);
    binA_kernel<<<NE / CHUNK, 256, 0, stream>>>(ei, ei + NE, et, cursors, stag8);
    binB_kernel<<<NCB, 256, 0, stream>>>(stag8, cursors, packed4, tile_start, tile_cnt);
    fused_kernel<<<NTILE, 256, 0, stream>>>(x, packed4, tile_start, tile_cnt,
                                            wgt, root, bias, out);
}